// Round 1
// baseline (2088.736 us; speedup 1.0000x reference)
//
#include <hip/hip_runtime.h>

#define PAD 68

__device__ __forceinline__ float sigm_(float x) { return 1.0f / (1.0f + __expf(-x)); }
__device__ __forceinline__ float tanh_(float x) {
    x = fminf(fmaxf(x, -15.0f), 15.0f);
    const float e = __expf(2.0f * x);
    return (e - 1.0f) / (e + 1.0f);
}

// One workgroup per batch row b. 256 threads = 32 node-groups x 8 lanes.
// All 3 message-passing iterations + final MLP fused; state lives in LDS.
__global__ __launch_bounds__(256, 4) void gnn_fused(
    const float* __restrict__ init_features,  // (B,32,3)
    const float* __restrict__ edge_weight,    // (B,992)
    const float* __restrict__ noise_info,     // (B,1)
    const float* __restrict__ hx_init,        // (B,32,64)
    const float* __restrict__ x_hat,          // (B,32)
    const float* __restrict__ var_in,         // (B,32)
    const float* __restrict__ W1a, const float* __restrict__ b1a,
    const float* __restrict__ W2a, const float* __restrict__ b2a,
    const float* __restrict__ W2b, const float* __restrict__ b2b,
    const float* __restrict__ W2c, const float* __restrict__ b2c,
    const float* __restrict__ W3a, const float* __restrict__ b3a,
    const float* __restrict__ W3b, const float* __restrict__ b3b,
    const float* __restrict__ W3c, const float* __restrict__ b3c,
    const float* __restrict__ Wih, const float* __restrict__ Whh,
    const float* __restrict__ bih, const float* __restrict__ bhh,
    const float* __restrict__ W4,  const float* __restrict__ b4,
    float* __restrict__ out)                  // (B,32,4)
{
    const int b = blockIdx.x;
    const int t = threadIdx.x;
    const int a = t >> 3;   // node index this thread serves (0..31)
    const int s = t & 7;    // sub-lane within node group (0..7)

    __shared__ float s_edge[992];
    __shared__ float s_A1[32][PAD];   // nodes[u] @ W2a[0:8]  + b2a   (pad 68: bank spread)
    __shared__ float s_B1[32][PAD];   // nodes[u] @ W2a[8:16]
    __shared__ float s_hx[32][PAD];   // GRU hidden state
    __shared__ float s_nodes[32][8];  // node features / gru_read
    __shared__ float s_summ[32][8];   // per-node message sums

    // --- stage constant-per-b data ---
    for (int i = t; i < 992; i += 256) s_edge[i] = edge_weight[(size_t)b*992 + i];
    const float nw = noise_info[b];
    for (int i = t; i < 2048; i += 256) s_hx[i >> 6][i & 63] = hx_init[(size_t)b*2048 + i];

    // --- iteration-0 nodes: x_init(5) @ W1a(5,8) + b1a ---
    {
        const float* f = init_features + ((size_t)b*32 + a)*3;
        float xi[5];
        xi[0] = f[0]; xi[1] = f[1]; xi[2] = f[2];
        xi[3] = x_hat[(size_t)b*32 + a];
        xi[4] = var_in[(size_t)b*32 + a];
        float acc = b1a[s];
        #pragma unroll
        for (int k = 0; k < 5; ++k) acc = __builtin_fmaf(xi[k], W1a[k*8+s], acc);
        s_nodes[a][s] = acc;
    }
    __syncthreads();

    for (int it = 0; it < 3; ++it) {
        // --- A1/B1 precompute: folds layer-1 node contributions (2304 -> ~256 FLOP/edge) ---
        {
            float nd[8];
            #pragma unroll
            for (int k = 0; k < 8; ++k) nd[k] = s_nodes[a][k];
            #pragma unroll
            for (int hh = 0; hh < 8; ++hh) {
                const int h = s*8 + hh;
                float accA = b2a[h];
                float accB = 0.0f;
                #pragma unroll
                for (int k = 0; k < 8; ++k) {
                    accA = __builtin_fmaf(nd[k], W2a[k*64 + h], accA);
                    accB = __builtin_fmaf(nd[k], W2a[(8+k)*64 + h], accB);
                }
                s_A1[a][h] = accA;
                s_B1[a][h] = accB;
            }
        }
        __syncthreads();

        // --- edge MLP: 8 lanes per node a, each lane does edges j = r*8+s ---
        float accout[8];
        #pragma unroll
        for (int c = 0; c < 8; ++c) accout[c] = 0.0f;

        for (int r = 0; r < 4; ++r) {
            const int j = r*8 + s;
            if (j < 31) {
                const int tb = (j < a) ? j : (j + 1);
                const float ew = s_edge[a*31 + j];
                float m2[32];
                #pragma unroll
                for (int n = 0; n < 32; ++n) m2[n] = b2b[n];
                for (int kb = 0; kb < 4; ++kb) {           // stream layer1 -> layer2 in k-blocks of 16
                    float m1[16];
                    #pragma unroll
                    for (int q = 0; q < 4; ++q) {
                        const int h = kb*16 + q*4;
                        const float4 A4 = *(const float4*)&s_A1[a][h];
                        const float4 B4 = *(const float4*)&s_B1[tb][h];
                        m1[q*4+0] = fmaxf(A4.x + B4.x + ew*W2a[1024+h  ] + nw*W2a[1088+h  ], 0.f);
                        m1[q*4+1] = fmaxf(A4.y + B4.y + ew*W2a[1024+h+1] + nw*W2a[1088+h+1], 0.f);
                        m1[q*4+2] = fmaxf(A4.z + B4.z + ew*W2a[1024+h+2] + nw*W2a[1088+h+2], 0.f);
                        m1[q*4+3] = fmaxf(A4.w + B4.w + ew*W2a[1024+h+3] + nw*W2a[1088+h+3], 0.f);
                    }
                    #pragma unroll
                    for (int kk = 0; kk < 16; ++kk) {      // weights uniform -> SGPR, v_fmac v,s,v
                        const int h = kb*16 + kk;
                        #pragma unroll
                        for (int n = 0; n < 32; ++n)
                            m2[n] = __builtin_fmaf(m1[kk], W2b[h*32+n], m2[n]);
                    }
                }
                #pragma unroll
                for (int c = 0; c < 8; ++c) {
                    float acc = b2c[c];
                    #pragma unroll
                    for (int n = 0; n < 32; ++n)
                        acc = __builtin_fmaf(fmaxf(m2[n], 0.f), W2c[n*8+c], acc);
                    accout[c] += fmaxf(acc, 0.f);
                }
            }
        }
        // reduce the 8 lanes of each node group; lane s keeps channel s
        #pragma unroll
        for (int mask = 1; mask < 8; mask <<= 1) {
            #pragma unroll
            for (int c = 0; c < 8; ++c)
                accout[c] += __shfl_xor(accout[c], mask, 64);
        }
        s_summ[a][s] = accout[s];
        __syncthreads();

        // --- GRU: thread handles channels c = s*8..s*8+7 of row (b,a); no cross-thread deps ---
        float hnew[8];
        {
            float x8[8];
            #pragma unroll
            for (int k = 0; k < 8; ++k) x8[k] = s_summ[a][k];
            #pragma unroll
            for (int cc = 0; cc < 8; ++cc) {
                const int c = s*8 + cc;
                float gir = bih[c], giz = bih[64+c], gin = bih[128+c];
                #pragma unroll
                for (int k = 0; k < 8; ++k) {
                    gir = __builtin_fmaf(x8[k], Wih[c*8+k],       gir);
                    giz = __builtin_fmaf(x8[k], Wih[(64+c)*8+k],  giz);
                    gin = __builtin_fmaf(x8[k], Wih[(128+c)*8+k], gin);
                }
                float ghr = bhh[c], ghz = bhh[64+c], ghn = bhh[128+c];
                #pragma unroll
                for (int k = 0; k < 64; ++k) {
                    const float hk = s_hx[a][k];
                    ghr = __builtin_fmaf(hk, Whh[c*64+k],       ghr);
                    ghz = __builtin_fmaf(hk, Whh[(64+c)*64+k],  ghz);
                    ghn = __builtin_fmaf(hk, Whh[(128+c)*64+k], ghn);
                }
                const float rr = sigm_(gir + ghr);
                const float zz = sigm_(giz + ghz);
                const float nn = tanh_(gin + rr*ghn);
                hnew[cc] = (1.0f - zz)*nn + zz*s_hx[a][c];
            }
        }
        __syncthreads();   // all s_hx reads done before overwrite
        #pragma unroll
        for (int cc = 0; cc < 8; ++cc) s_hx[a][s*8+cc] = hnew[cc];
        __syncthreads();

        // --- gru_read / next nodes: hx(64) @ W4(64,8) + b4 ---
        {
            float acc = b4[s];
            #pragma unroll
            for (int k = 0; k < 64; ++k)
                acc = __builtin_fmaf(s_hx[a][k], W4[k*8+s], acc);
            s_nodes[a][s] = acc;
        }
        __syncthreads();
    }

    // --- final MLP (no activations): 8 -> 64 -> 32 -> 4 ---
    {
        float nd[8];
        #pragma unroll
        for (int k = 0; k < 8; ++k) nd[k] = s_nodes[a][k];
        #pragma unroll
        for (int hh = 0; hh < 8; ++hh) {
            const int h = s*8 + hh;
            float acc = b3a[h];
            #pragma unroll
            for (int k = 0; k < 8; ++k) acc = __builtin_fmaf(nd[k], W3a[k*64+h], acc);
            s_A1[a][h] = acc;      // reuse s_A1 as v1 scratch
        }
    }
    __syncthreads();
    {
        float acc[4];
        #pragma unroll
        for (int i = 0; i < 4; ++i) acc[i] = b3b[s*4+i];
        #pragma unroll
        for (int k = 0; k < 64; ++k) {
            const float v = s_A1[a][k];
            #pragma unroll
            for (int i = 0; i < 4; ++i)
                acc[i] = __builtin_fmaf(v, W3b[k*32 + s*4 + i], acc[i]);
        }
        #pragma unroll
        for (int i = 0; i < 4; ++i) s_B1[a][s*4+i] = acc[i];   // reuse s_B1 as v2 scratch
    }
    __syncthreads();
    if (s < 4) {
        float acc = b3c[s];
        #pragma unroll
        for (int n = 0; n < 32; ++n)
            acc = __builtin_fmaf(s_B1[a][n], W3c[n*4+s], acc);
        out[((size_t)b*32 + a)*4 + s] = acc;
    }
}

extern "C" void kernel_launch(void* const* d_in, const int* in_sizes, int n_in,
                              void* d_out, int out_size, void* d_ws, size_t ws_size,
                              hipStream_t stream)
{
    const float* init_features = (const float*)d_in[0];
    const float* edge_weight   = (const float*)d_in[1];
    const float* noise_info    = (const float*)d_in[2];
    const float* hx_init       = (const float*)d_in[3];
    /* d_in[4] = cons — unused by the reference forward */
    const float* x_hat = (const float*)d_in[5];
    const float* var_i = (const float*)d_in[6];
    const float* W1a = (const float*)d_in[7];  const float* b1a = (const float*)d_in[8];
    const float* W2a = (const float*)d_in[9];  const float* b2a = (const float*)d_in[10];
    const float* W2b = (const float*)d_in[11]; const float* b2b = (const float*)d_in[12];
    const float* W2c = (const float*)d_in[13]; const float* b2c = (const float*)d_in[14];
    const float* W3a = (const float*)d_in[15]; const float* b3a = (const float*)d_in[16];
    const float* W3b = (const float*)d_in[17]; const float* b3b = (const float*)d_in[18];
    const float* W3c = (const float*)d_in[19]; const float* b3c = (const float*)d_in[20];
    const float* Wih = (const float*)d_in[21]; const float* Whh = (const float*)d_in[22];
    const float* bih = (const float*)d_in[23]; const float* bhh = (const float*)d_in[24];
    const float* W4  = (const float*)d_in[25]; const float* b4  = (const float*)d_in[26];

    gnn_fused<<<dim3(1024), dim3(256), 0, stream>>>(
        init_features, edge_weight, noise_info, hx_init, x_hat, var_i,
        W1a, b1a, W2a, b2a, W2b, b2b, W2c, b2c,
        W3a, b3a, W3b, b3b, W3c, b3c,
        Wih, Whh, bih, bhh, W4, b4, (float*)d_out);
}